// Round 3
// baseline (430.100 us; speedup 1.0000x reference)
//
#include <hip/hip_runtime.h>
#include <hip/hip_fp16.h>
#include <math.h>

#define N_NODES 100000
#define N_EDGES 1600000
#define LN_EPS 1e-5f
#define NORM_EPS 1e-12f
#define SCAN_TILE 1024
#define N_TILES ((N_NODES + SCAN_TILE - 1) / SCAN_TILE)   // 98
#define ROWS_PER_BLOCK 32
#define GEMM_BLOCKS (N_NODES / ROWS_PER_BLOCK)            // 3125, exact
#define WSTRIDE 66   // even (b64-aligned) and 2c+k -> 2-way banks (free)
#define REC_BYTES 32 // final per-edge record {half alpha[8]; int dst; pad}
                     // R12 ERRATA: 64B full-line records FAILED (FETCH flat at
                     // 140MB, WRITE +67MB = exactly the pad payload): TCC
                     // write-allocates on scattered partial stores regardless
                     // of coverage; L3 does not absorb dirty scatter WBs
                     // (WRITE = 2x region = one WB per claiming XCD per line).
                     // => cost is TOUCH COUNT.  R13: two-pass binned scatter.
#define BKT_SLOTS 4096                                     // 128KB final window
#define BKT_SHIFT 12
#define NB ((N_EDGES + BKT_SLOTS - 1) / BKT_SLOTS)         // 391 buckets
#define NXCD 8
#define SCAP 576     // per-(xcd,bucket) staging cap: E=512, sigma~21, +3sigma;
                     // overflow falls back to direct scattered write (rare)

// ---------------------------------------------------------------------------
// K1: h = x @ W^T + b (N x 64) -> fp16 (|h|~6 << 65504; 8x less quant error
// than bf16); per-node attn scores fp32; fused edge count (atomics AFTER the
// k-loop).  K-LOOP DELIBERATELY NOT UNROLLED (#pragma unroll 1): R5/R6
// measured the unrolled version spilling acc[] at ANY VGPR budget (2.0/0.95
// GB scratch writes).  No min-waves hint (R5: it's a VGPR cap -> spills).
// NO nontemporal hints (R9: neutral/negative).  NO cooperative launch (R10:
// grid.sync ~200us each on 8-XCD gfx950).
// ---------------------------------------------------------------------------
__global__ __launch_bounds__(256) void k_gemm(
    const float* __restrict__ x, const float* __restrict__ W,
    const float* __restrict__ b, const float* __restrict__ a,
    const int* __restrict__ ei, int* __restrict__ counts,
    __half* __restrict__ h16,
    float* __restrict__ s_src, float* __restrict__ s_dst)
{
    __shared__ float WL[64 * WSTRIDE];            // WL[c*66 + k] = W[c][k]
    __shared__ float xs[ROWS_PER_BLOCK * 64];
    const int tid  = threadIdx.x;
    const int lane = tid & 63;
    const int wv   = tid >> 6;

    for (int idx = tid * 4; idx < 64 * 64; idx += 256 * 4) {
        const float4 w = *(const float4*)(W + idx);
        const int c = idx >> 6, k = idx & 63;
        WL[c * WSTRIDE + k + 0] = w.x;
        WL[c * WSTRIDE + k + 1] = w.y;
        WL[c * WSTRIDE + k + 2] = w.z;
        WL[c * WSTRIDE + k + 3] = w.w;
    }
    const int row0 = blockIdx.x * ROWS_PER_BLOCK;
    for (int idx = tid * 4; idx < ROWS_PER_BLOCK * 64; idx += 256 * 4)
        *(float4*)(xs + idx) = *(const float4*)(x + (size_t)row0 * 64 + idx);
    __syncthreads();

    const float bias = b[lane];
    float acc[8];
    #pragma unroll
    for (int r = 0; r < 8; ++r) acc[r] = bias;

    const int rbase = wv * 8;
    const float* wrow = WL + lane * WSTRIDE;
    const float* xrow = xs + rbase * 64;
    #pragma unroll 1   // DO NOT unroll: keeps live set small (see header)
    for (int kk = 0; kk < 64; kk += 4) {
        const float2 w01 = *(const float2*)(wrow + kk);
        const float2 w23 = *(const float2*)(wrow + kk + 2);
        #pragma unroll
        for (int r = 0; r < 8; ++r) {
            const float4 xq = *(const float4*)(xrow + r * 64 + kk);
            acc[r] += xq.x * w01.x + xq.y * w01.y + xq.z * w23.x + xq.w * w23.y;
        }
    }

    // fused out-degree count: no __syncthreads after this point
    {
        const int e0 = blockIdx.x * 256 + tid;
        atomicAdd(&counts[ei[e0]], 1);
        atomicAdd(&counts[ei[e0 + GEMM_BLOCKS * 256]], 1);
    }

    const float asrc = a[(lane >> 3) * 16 + (lane & 7)];
    const float adst = a[(lane >> 3) * 16 + 8 + (lane & 7)];
    #pragma unroll
    for (int r = 0; r < 8; ++r) {
        const int row = row0 + rbase + r;
        const float v = acc[r];
        h16[(size_t)row * 64 + lane] = __float2half_rn(v);
        float p = v * asrc, q = v * adst;
        p += __shfl_xor(p, 1);  q += __shfl_xor(q, 1);
        p += __shfl_xor(p, 2);  q += __shfl_xor(q, 2);
        p += __shfl_xor(p, 4);  q += __shfl_xor(q, 4);
        if ((lane & 7) == 0) {
            s_src[row * 8 + (lane >> 3)] = p;
            s_dst[row * 8 + (lane >> 3)] = q;
        }
    }
}

// ---------------------------------------------------------------------------
// Scan stage 1: per-tile (1024) exclusive scan + tile totals.
// ---------------------------------------------------------------------------
__global__ __launch_bounds__(1024) void k_scan1(
    const int* __restrict__ counts, int* __restrict__ row_ptr,
    int* __restrict__ blksum)
{
    __shared__ int wsum[16];
    const int tid = threadIdx.x, lane = tid & 63, wv = tid >> 6;
    const int i = blockIdx.x * SCAN_TILE + tid;
    int v = (i < N_NODES) ? counts[i] : 0;
    int sc = v;
    #pragma unroll
    for (int off = 1; off < 64; off <<= 1) {
        int t = __shfl_up(sc, off);
        if (lane >= off) sc += t;
    }
    if (lane == 63) wsum[wv] = sc;
    __syncthreads();
    if (tid < 16) {
        int ws = wsum[tid];
        #pragma unroll
        for (int off = 1; off < 16; off <<= 1) {
            int t = __shfl_up(ws, off);
            if (tid >= off) ws += t;
        }
        wsum[tid] = ws;
    }
    __syncthreads();
    const int pref = wv ? wsum[wv - 1] : 0;
    if (i < N_NODES) row_ptr[i] = pref + sc - v;   // tile-local exclusive
    if (tid == 0) blksum[blockIdx.x] = wsum[15];
}

// ---------------------------------------------------------------------------
// Scan stages 2+3 fused: redundant 98-element scan per block, add-back,
// cursor init.
// ---------------------------------------------------------------------------
__global__ __launch_bounds__(256) void k_scan23(
    int* __restrict__ row_ptr, const int* __restrict__ blksum,
    int* __restrict__ cursor)
{
    __shared__ int spref[N_TILES];
    const int tid = threadIdx.x;
    if (tid < 64) {
        int v0 = (tid < N_TILES) ? blksum[tid] : 0;
        int s0 = v0;
        #pragma unroll
        for (int off = 1; off < 64; off <<= 1) {
            int t = __shfl_up(s0, off);
            if (tid >= off) s0 += t;
        }
        if (tid < N_TILES) spref[tid] = s0 - v0;
        int carry = __shfl(s0, 63);
        int i2 = 64 + tid;
        int v1 = (i2 < N_TILES) ? blksum[i2] : 0;
        int s1 = v1;
        #pragma unroll
        for (int off = 1; off < 64; off <<= 1) {
            int t = __shfl_up(s1, off);
            if (tid >= off) s1 += t;
        }
        if (i2 < N_TILES) spref[i2] = carry + s1 - v1;
    }
    __syncthreads();
    const int i = blockIdx.x * 256 + tid;
    if (i < N_NODES) {
        int r = row_ptr[i] + spref[i >> 10];
        row_ptr[i] = r;
        cursor[i] = r;
    }
    if (i == 0) row_ptr[N_NODES] = N_EDGES;
}

// ---------------------------------------------------------------------------
// Fill pass 1: one THREAD per edge.  Computes alpha + exact final slot
// (cursor atomic) as before, but stages the record into a bin keyed by
// (xcd-hint = blockIdx&7, bucket = slot>>12).  Bin frontiers advance
// sequentially and are XCD-private -> the 2 records sharing a 64B line
// merge in ONE L2 before writeback (touch-count fix).  xcd-hint is a pure
// locality hint: wrong mapping degrades perf only, never correctness.
// Overflow past SCAP -> direct scattered write to rec[] (rare, ~0.1% bins).
// ---------------------------------------------------------------------------
__global__ __launch_bounds__(256) void k_fill_p1(
    const int* __restrict__ ei, int* __restrict__ cursor,
    const float* __restrict__ s_src, const float* __restrict__ s_dst,
    int* __restrict__ scur, char* __restrict__ staging,
    char* __restrict__ rec)
{
    const int e = blockIdx.x * 256 + threadIdx.x;
    if (e >= N_EDGES) return;
    const int src = ei[e];
    const int dst = ei[N_EDGES + e];
    const int slot = atomicAdd(&cursor[src], 1);

    const float4 a0 = *(const float4*)(s_src + (size_t)src * 8);
    const float4 a1 = *(const float4*)(s_src + (size_t)src * 8 + 4);
    const float4 b0 = *(const float4*)(s_dst + (size_t)dst * 8);
    const float4 b1 = *(const float4*)(s_dst + (size_t)dst * 8 + 4);
    float sc[8] = {a0.x + b0.x, a0.y + b0.y, a0.z + b0.z, a0.w + b0.w,
                   a1.x + b1.x, a1.y + b1.y, a1.z + b1.z, a1.w + b1.w};
    float m = -1e30f;
    #pragma unroll
    for (int h = 0; h < 8; ++h) {
        sc[h] = (sc[h] >= 0.f) ? sc[h] : 0.2f * sc[h];
        m = fmaxf(m, sc[h]);
    }
    float sum = 0.f;
    #pragma unroll
    for (int h = 0; h < 8; ++h) { sc[h] = __expf(sc[h] - m); sum += sc[h]; }
    const float inv = 1.f / sum;
    unsigned int q[4];
    #pragma unroll
    for (int j = 0; j < 4; ++j) {
        const unsigned short lo = __half_as_ushort(__float2half_rn(sc[2*j]   * inv));
        const unsigned short hi = __half_as_ushort(__float2half_rn(sc[2*j+1] * inv));
        q[j] = (unsigned int)lo | ((unsigned int)hi << 16);
    }
    const uint4 pk = make_uint4(q[0], q[1], q[2], q[3]);

    const int xcdh = blockIdx.x & (NXCD - 1);
    const int bkt  = slot >> BKT_SHIFT;
    const int reg  = xcdh * NB + bkt;
    const int ss   = atomicAdd(&scur[reg], 1);
    if (ss < SCAP) {
        char* p = staging + ((size_t)reg * SCAP + ss) * 32;
        *(uint4*)p        = pk;
        *(uint4*)(p + 16) = make_uint4((unsigned)dst, (unsigned)slot, 0u, 0u);
    } else {
        char* r = rec + (size_t)slot * REC_BYTES;       // rare fallback
        *(uint4*)r        = pk;
        *(uint4*)(r + 16) = make_uint4((unsigned)dst, 0u, 0u, 0u);
    }
}

// ---------------------------------------------------------------------------
// Fill pass 2: ONE block per bucket.  Reads the bucket's 8 staging bins
// sequentially (coalesced) and scatters into the bucket's 128KB window of
// rec[] — all through this block's single CU/L2 -> window L2-resident,
// each final line written back ONCE with both records merged.
// ---------------------------------------------------------------------------
__global__ __launch_bounds__(1024) void k_fill_p2(
    const int* __restrict__ scur, const char* __restrict__ staging,
    char* __restrict__ rec)
{
    const int g = blockIdx.x;
    #pragma unroll 1
    for (int x = 0; x < NXCD; ++x) {
        const int reg = x * NB + g;
        const int n = min(scur[reg], SCAP);
        for (int j = threadIdx.x; j < n; j += 1024) {
            const char* p = staging + ((size_t)reg * SCAP + j) * 32;
            const uint4 pk = *(const uint4*)p;
            const uint4 md = *(const uint4*)(p + 16);
            char* r = rec + (size_t)md.y * REC_BYTES;
            *(uint4*)r        = pk;
            *(uint4*)(r + 16) = make_uint4(md.x, 0u, 0u, 0u);
        }
    }
}

// ---------------------------------------------------------------------------
// Gather + epilogue: one wave per node; slim loop (~8-10 instrs/edge):
// sequential 32 B record stream (alpha fp16 + dst), random 128 B h16 row
// (L3-resident), FMA.  Identical to R11's verified version.
// ---------------------------------------------------------------------------
__global__ __launch_bounds__(256) void k_gather(
    const int* __restrict__ row_ptr, const char* __restrict__ rec,
    const __half* __restrict__ h16,
    const float* __restrict__ x, const float* __restrict__ ln_scale,
    const float* __restrict__ ln_bias, float* __restrict__ out)
{
    const int i = blockIdx.x * 4 + (threadIdx.x >> 6);
    if (i >= N_NODES) return;
    const int lane = threadIdx.x & 63;
    const int head = lane >> 3;

    const int beg = row_ptr[i];
    const int end = row_ptr[i + 1];
    const float xres = x[(size_t)i * 64 + lane];

    float acc = 0.f;
    int e = beg;
    for (; e + 3 < end; e += 4) {
        const char* r0 = rec + (size_t)(e + 0) * REC_BYTES;
        const char* r1 = rec + (size_t)(e + 1) * REC_BYTES;
        const char* r2 = rec + (size_t)(e + 2) * REC_BYTES;
        const char* r3 = rec + (size_t)(e + 3) * REC_BYTES;
        const int d0 = *(const int*)(r0 + 16);
        const int d1 = *(const int*)(r1 + 16);
        const int d2 = *(const int*)(r2 + 16);
        const int d3 = *(const int*)(r3 + 16);
        const float al0 = __half2float(*(const __half*)(r0 + (head << 1)));
        const float al1 = __half2float(*(const __half*)(r1 + (head << 1)));
        const float al2 = __half2float(*(const __half*)(r2 + (head << 1)));
        const float al3 = __half2float(*(const __half*)(r3 + (head << 1)));
        const float h0 = __half2float(h16[(size_t)d0 * 64 + lane]);
        const float h1 = __half2float(h16[(size_t)d1 * 64 + lane]);
        const float h2 = __half2float(h16[(size_t)d2 * 64 + lane]);
        const float h3 = __half2float(h16[(size_t)d3 * 64 + lane]);
        acc += al0 * h0 + al1 * h1 + al2 * h2 + al3 * h3;
    }
    for (; e < end; ++e) {
        const char* r = rec + (size_t)e * REC_BYTES;
        acc += __half2float(*(const __half*)(r + (head << 1))) *
               __half2float(h16[(size_t)(*(const int*)(r + 16)) * 64 + lane]);
    }

    // epilogue: residual + LayerNorm + L2 normalize
    float v = acc + xres;
    float s = v;
    #pragma unroll
    for (int off = 1; off < 64; off <<= 1) s += __shfl_xor(s, off);
    const float mu = s * (1.f / 64.f);
    const float d = v - mu;
    float vs = d * d;
    #pragma unroll
    for (int off = 1; off < 64; off <<= 1) vs += __shfl_xor(vs, off);
    const float var = vs * (1.f / 64.f);
    float y = d * rsqrtf(var + LN_EPS) * ln_scale[lane] + ln_bias[lane];
    float ss = y * y;
    #pragma unroll
    for (int off = 1; off < 64; off <<= 1) ss += __shfl_xor(ss, off);
    const float norm = sqrtf(ss);
    out[(size_t)i * 64 + lane] = y / fmaxf(norm, NORM_EPS);
}

// ---------------------------------------------------------------------------
extern "C" void kernel_launch(void* const* d_in, const int* in_sizes, int n_in,
                              void* d_out, int out_size, void* d_ws, size_t ws_size,
                              hipStream_t stream)
{
    const float* x        = (const float*)d_in[0];
    const int*   ei       = (const int*)d_in[1];
    const float* W        = (const float*)d_in[2];
    const float* b        = (const float*)d_in[3];
    const float* a        = (const float*)d_in[4];
    const float* ln_scale = (const float*)d_in[5];
    const float* ln_bias  = (const float*)d_in[6];
    float* out = (float*)d_out;

    char* ws = (char*)d_ws;
    size_t off = 0;
    auto alloc = [&](size_t bytes) {
        void* p = ws + off;
        off = (off + bytes + 255) & ~(size_t)255;
        return p;
    };
    __half* h16       = (__half*)alloc((size_t)N_NODES * 64 * 2);
    float* s_src      = (float*) alloc((size_t)N_NODES * 8 * 4);
    float* s_dst      = (float*) alloc((size_t)N_NODES * 8 * 4);
    int*   counts     = (int*)   alloc((size_t)N_NODES * 4);
    int*   row_ptr    = (int*)   alloc((size_t)(N_NODES + 1) * 4);
    int*   cursor     = (int*)   alloc((size_t)N_NODES * 4);
    int*   blksum     = (int*)   alloc((size_t)N_TILES * 4);
    int*   scur       = (int*)   alloc((size_t)NXCD * NB * 4);
    char*  rec        = (char*)  alloc((size_t)N_EDGES * REC_BYTES);
    char*  staging    = (char*)  alloc((size_t)NXCD * NB * SCAP * 32);

    hipMemsetAsync(counts, 0, (size_t)N_NODES * 4, stream);
    hipMemsetAsync(scur,   0, (size_t)NXCD * NB * 4, stream);

    k_gemm   <<<GEMM_BLOCKS, 256, 0, stream>>>(x, W, b, a, ei, counts,
                                               h16, s_src, s_dst);
    k_scan1  <<<N_TILES, 1024, 0, stream>>>(counts, row_ptr, blksum);
    k_scan23 <<<(N_NODES + 255) / 256, 256, 0, stream>>>(row_ptr, blksum, cursor);
    k_fill_p1<<<(N_EDGES + 255) / 256, 256, 0, stream>>>(ei, cursor, s_src, s_dst,
                                                         scur, staging, rec);
    k_fill_p2<<<NB, 1024, 0, stream>>>(scur, staging, rec);
    k_gather <<<(N_NODES + 3) / 4,     256, 0, stream>>>(row_ptr, rec,
                                                         h16, x,
                                                         ln_scale, ln_bias, out);
}

// Round 4
// 291.932 us; speedup vs baseline: 1.4733x; 1.4733x over previous
//
#include <hip/hip_runtime.h>
#include <hip/hip_fp16.h>
#include <math.h>

#define N_NODES 100000
#define N_EDGES 1600000
#define LN_EPS 1e-5f
#define NORM_EPS 1e-12f
#define SCAN_TILE 1024
#define N_TILES ((N_NODES + SCAN_TILE - 1) / SCAN_TILE)   // 98
#define ROWS_PER_BLOCK 32
#define GEMM_BLOCKS (N_NODES / ROWS_PER_BLOCK)            // 3125, exact
#define WSTRIDE 66   // even (b64-aligned) and 2c+k -> 2-way banks (free)
#define REC_BYTES 32 // final per-edge record {half alpha[8]; int dst; pad}
// R12/R13 ERRATA (measured): scattered partial-line stores pay a full 64B
// fetch+WB PER TOUCH whenever consecutive records of a line are written by
// different workgroups (R1: WRITE=touches*64B; R2 full-line pad: +67MB WRITE,
// FETCH flat; R3 XCD-hinted staging bins: WRITE 2.6x payload, 155us).
// Invariant learned: coalescing happens ONLY when one block (one CU/L2)
// owns all writes to a line.  R14: bucketed counting sort -- k_bin makes
// block-local runs; k_place gives each block an exclusive 33KB rec window.
#define WB 64                                   // nodes per place-bucket
#define NBKT ((N_NODES + WB - 1) / WB)          // 1563
#define BIN_TILE 8192                           // 1024 thr x 8 edges
#define BIN_BLOCKS ((N_EDGES + BIN_TILE - 1) / BIN_TILE)  // 196

// ---------------------------------------------------------------------------
// K1: h = x @ W^T + b (N x 64) -> fp16 (|h|~6 << 65504; 8x less quant error
// than bf16); per-node attn scores fp32; fused edge count (atomics AFTER the
// k-loop).  K-LOOP DELIBERATELY NOT UNROLLED (#pragma unroll 1): R5/R6
// measured the unrolled version spilling acc[] at ANY VGPR budget (2.0/0.95
// GB scratch writes).  No min-waves hint (R5: it's a VGPR cap -> spills).
// NO nontemporal hints (R9: neutral/negative).  NO cooperative launch (R10:
// grid.sync ~200us each on 8-XCD gfx950).
// ---------------------------------------------------------------------------
__global__ __launch_bounds__(256) void k_gemm(
    const float* __restrict__ x, const float* __restrict__ W,
    const float* __restrict__ b, const float* __restrict__ a,
    const int* __restrict__ ei, int* __restrict__ counts,
    __half* __restrict__ h16,
    float* __restrict__ s_src, float* __restrict__ s_dst)
{
    __shared__ float WL[64 * WSTRIDE];            // WL[c*66 + k] = W[c][k]
    __shared__ float xs[ROWS_PER_BLOCK * 64];
    const int tid  = threadIdx.x;
    const int lane = tid & 63;
    const int wv   = tid >> 6;

    for (int idx = tid * 4; idx < 64 * 64; idx += 256 * 4) {
        const float4 w = *(const float4*)(W + idx);
        const int c = idx >> 6, k = idx & 63;
        WL[c * WSTRIDE + k + 0] = w.x;
        WL[c * WSTRIDE + k + 1] = w.y;
        WL[c * WSTRIDE + k + 2] = w.z;
        WL[c * WSTRIDE + k + 3] = w.w;
    }
    const int row0 = blockIdx.x * ROWS_PER_BLOCK;
    for (int idx = tid * 4; idx < ROWS_PER_BLOCK * 64; idx += 256 * 4)
        *(float4*)(xs + idx) = *(const float4*)(x + (size_t)row0 * 64 + idx);
    __syncthreads();

    const float bias = b[lane];
    float acc[8];
    #pragma unroll
    for (int r = 0; r < 8; ++r) acc[r] = bias;

    const int rbase = wv * 8;
    const float* wrow = WL + lane * WSTRIDE;
    const float* xrow = xs + rbase * 64;
    #pragma unroll 1   // DO NOT unroll: keeps live set small (see header)
    for (int kk = 0; kk < 64; kk += 4) {
        const float2 w01 = *(const float2*)(wrow + kk);
        const float2 w23 = *(const float2*)(wrow + kk + 2);
        #pragma unroll
        for (int r = 0; r < 8; ++r) {
            const float4 xq = *(const float4*)(xrow + r * 64 + kk);
            acc[r] += xq.x * w01.x + xq.y * w01.y + xq.z * w23.x + xq.w * w23.y;
        }
    }

    // fused out-degree count: no __syncthreads after this point
    {
        const int e0 = blockIdx.x * 256 + tid;
        atomicAdd(&counts[ei[e0]], 1);
        atomicAdd(&counts[ei[e0 + GEMM_BLOCKS * 256]], 1);
    }

    const float asrc = a[(lane >> 3) * 16 + (lane & 7)];
    const float adst = a[(lane >> 3) * 16 + 8 + (lane & 7)];
    #pragma unroll
    for (int r = 0; r < 8; ++r) {
        const int row = row0 + rbase + r;
        const float v = acc[r];
        h16[(size_t)row * 64 + lane] = __float2half_rn(v);
        float p = v * asrc, q = v * adst;
        p += __shfl_xor(p, 1);  q += __shfl_xor(q, 1);
        p += __shfl_xor(p, 2);  q += __shfl_xor(q, 2);
        p += __shfl_xor(p, 4);  q += __shfl_xor(q, 4);
        if ((lane & 7) == 0) {
            s_src[row * 8 + (lane >> 3)] = p;
            s_dst[row * 8 + (lane >> 3)] = q;
        }
    }
}

// ---------------------------------------------------------------------------
// Scan stage 1: per-tile (1024) exclusive scan + tile totals.
// ---------------------------------------------------------------------------
__global__ __launch_bounds__(1024) void k_scan1(
    const int* __restrict__ counts, int* __restrict__ row_ptr,
    int* __restrict__ blksum)
{
    __shared__ int wsum[16];
    const int tid = threadIdx.x, lane = tid & 63, wv = tid >> 6;
    const int i = blockIdx.x * SCAN_TILE + tid;
    int v = (i < N_NODES) ? counts[i] : 0;
    int sc = v;
    #pragma unroll
    for (int off = 1; off < 64; off <<= 1) {
        int t = __shfl_up(sc, off);
        if (lane >= off) sc += t;
    }
    if (lane == 63) wsum[wv] = sc;
    __syncthreads();
    if (tid < 16) {
        int ws = wsum[tid];
        #pragma unroll
        for (int off = 1; off < 16; off <<= 1) {
            int t = __shfl_up(ws, off);
            if (tid >= off) ws += t;
        }
        wsum[tid] = ws;
    }
    __syncthreads();
    const int pref = wv ? wsum[wv - 1] : 0;
    if (i < N_NODES) row_ptr[i] = pref + sc - v;   // tile-local exclusive
    if (tid == 0) blksum[blockIdx.x] = wsum[15];
}

// ---------------------------------------------------------------------------
// Scan stages 2+3 fused: redundant 98-element scan per block, add-back,
// bin-frontier init (gbin[b] = row_ptr[b*WB], consumed by k_bin).
// ---------------------------------------------------------------------------
__global__ __launch_bounds__(256) void k_scan23(
    int* __restrict__ row_ptr, const int* __restrict__ blksum,
    int* __restrict__ gbin)
{
    __shared__ int spref[N_TILES];
    const int tid = threadIdx.x;
    if (tid < 64) {
        int v0 = (tid < N_TILES) ? blksum[tid] : 0;
        int s0 = v0;
        #pragma unroll
        for (int off = 1; off < 64; off <<= 1) {
            int t = __shfl_up(s0, off);
            if (tid >= off) s0 += t;
        }
        if (tid < N_TILES) spref[tid] = s0 - v0;
        int carry = __shfl(s0, 63);
        int i2 = 64 + tid;
        int v1 = (i2 < N_TILES) ? blksum[i2] : 0;
        int s1 = v1;
        #pragma unroll
        for (int off = 1; off < 64; off <<= 1) {
            int t = __shfl_up(s1, off);
            if (tid >= off) s1 += t;
        }
        if (i2 < N_TILES) spref[i2] = carry + s1 - v1;
    }
    __syncthreads();
    const int i = blockIdx.x * 256 + tid;
    if (i < N_NODES) {
        int r = row_ptr[i] + spref[i >> 10];
        row_ptr[i] = r;
        if ((i & (WB - 1)) == 0) gbin[i / WB] = r;
    }
    if (i == 0) row_ptr[N_NODES] = N_EDGES;
}

// ---------------------------------------------------------------------------
// k_bin: bucket edges by src>>6 into NBKT=1563 buckets.  LDS histogram
// (atomic return = local rank), ONE global atomic per (block,bucket) claims
// a contiguous run, then each thread writes its {src,dst} int2 at base+rank.
// Writes within a run come from one block (one CU/L2) -> lines assemble
// locally; only run-boundary lines are shared across blocks (~20MB extra).
// Bucket segment bases come free from row_ptr via gbin -- exact sizes,
// no overflow paths, no XCD/dispatch assumptions.
// ---------------------------------------------------------------------------
__global__ __launch_bounds__(1024) void k_bin(
    const int* __restrict__ ei, int* __restrict__ gbin,
    int2* __restrict__ staged)
{
    __shared__ int hist[NBKT];
    __shared__ int base[NBKT];
    const int tid = threadIdx.x;
    for (int b = tid; b < NBKT; b += 1024) hist[b] = 0;
    __syncthreads();

    int s[8], d[8], r[8];
    const int e0 = blockIdx.x * BIN_TILE;
    #pragma unroll
    for (int j = 0; j < 8; ++j) {
        const int e = e0 + j * 1024 + tid;
        if (e < N_EDGES) {
            s[j] = ei[e];
            d[j] = ei[N_EDGES + e];
            r[j] = atomicAdd(&hist[s[j] >> 6], 1);
        }
    }
    __syncthreads();
    for (int b = tid; b < NBKT; b += 1024)
        if (hist[b]) base[b] = atomicAdd(&gbin[b], hist[b]);
    __syncthreads();
    #pragma unroll
    for (int j = 0; j < 8; ++j) {
        const int e = e0 + j * 1024 + tid;
        if (e < N_EDGES)
            staged[(size_t)base[s[j] >> 6] + r[j]] = make_int2(s[j], d[j]);
    }
}

// ---------------------------------------------------------------------------
// k_place: block g owns nodes [g*64, g*64+64).  Reads its staged segment
// [row_ptr[g*64], row_ptr[g*64+64]) SEQUENTIALLY, computes alpha (s_src
// slice is a 2KB contiguous range -> L1-hot; s_dst random but 3.2MB region
// ~L2-resident per XCD), assigns slots via LDS cursors (NO global cursor
// atomics), and writes records into the block's EXCLUSIVE ~33KB rec window:
// both records of every 64B line come from this block -> one WB per line.
// ---------------------------------------------------------------------------
__global__ __launch_bounds__(1024) void k_place(
    const int* __restrict__ row_ptr, const int2* __restrict__ staged,
    const float* __restrict__ s_src, const float* __restrict__ s_dst,
    char* __restrict__ rec)
{
    __shared__ int cur[WB];
    const int g  = blockIdx.x;
    const int n0 = g * WB;
    const int tid = threadIdx.x;
    if (tid < WB && n0 + tid < N_NODES) cur[tid] = row_ptr[n0 + tid];
    __syncthreads();
    const int beg = row_ptr[n0];
    const int end = row_ptr[min(n0 + WB, N_NODES)];

    for (int j = beg + tid; j < end; j += 1024) {
        const int2 sd = staged[j];
        const int src = sd.x, dst = sd.y;

        const float4 a0 = *(const float4*)(s_src + (size_t)src * 8);
        const float4 a1 = *(const float4*)(s_src + (size_t)src * 8 + 4);
        const float4 b0 = *(const float4*)(s_dst + (size_t)dst * 8);
        const float4 b1 = *(const float4*)(s_dst + (size_t)dst * 8 + 4);
        float sc[8] = {a0.x + b0.x, a0.y + b0.y, a0.z + b0.z, a0.w + b0.w,
                       a1.x + b1.x, a1.y + b1.y, a1.z + b1.z, a1.w + b1.w};
        float m = -1e30f;
        #pragma unroll
        for (int h = 0; h < 8; ++h) {
            sc[h] = (sc[h] >= 0.f) ? sc[h] : 0.2f * sc[h];
            m = fmaxf(m, sc[h]);
        }
        float sum = 0.f;
        #pragma unroll
        for (int h = 0; h < 8; ++h) { sc[h] = __expf(sc[h] - m); sum += sc[h]; }
        const float inv = 1.f / sum;
        unsigned int q[4];
        #pragma unroll
        for (int jj = 0; jj < 4; ++jj) {
            const unsigned short lo = __half_as_ushort(__float2half_rn(sc[2*jj]   * inv));
            const unsigned short hi = __half_as_ushort(__float2half_rn(sc[2*jj+1] * inv));
            q[jj] = (unsigned int)lo | ((unsigned int)hi << 16);
        }

        const int slot = atomicAdd(&cur[src - n0], 1);
        char* rcd = rec + (size_t)slot * REC_BYTES;
        *(uint4*)rcd        = make_uint4(q[0], q[1], q[2], q[3]);
        *(uint4*)(rcd + 16) = make_uint4((unsigned)dst, 0u, 0u, 0u);
    }
}

// ---------------------------------------------------------------------------
// Gather + epilogue: one wave per node; slim loop (~8-10 instrs/edge):
// sequential 32 B record stream (alpha fp16 + dst), random 128 B h16 row
// (L3-resident), FMA.  Identical to R11's verified version.
// ---------------------------------------------------------------------------
__global__ __launch_bounds__(256) void k_gather(
    const int* __restrict__ row_ptr, const char* __restrict__ rec,
    const __half* __restrict__ h16,
    const float* __restrict__ x, const float* __restrict__ ln_scale,
    const float* __restrict__ ln_bias, float* __restrict__ out)
{
    const int i = blockIdx.x * 4 + (threadIdx.x >> 6);
    if (i >= N_NODES) return;
    const int lane = threadIdx.x & 63;
    const int head = lane >> 3;

    const int beg = row_ptr[i];
    const int end = row_ptr[i + 1];
    const float xres = x[(size_t)i * 64 + lane];

    float acc = 0.f;
    int e = beg;
    for (; e + 3 < end; e += 4) {
        const char* r0 = rec + (size_t)(e + 0) * REC_BYTES;
        const char* r1 = rec + (size_t)(e + 1) * REC_BYTES;
        const char* r2 = rec + (size_t)(e + 2) * REC_BYTES;
        const char* r3 = rec + (size_t)(e + 3) * REC_BYTES;
        const int d0 = *(const int*)(r0 + 16);
        const int d1 = *(const int*)(r1 + 16);
        const int d2 = *(const int*)(r2 + 16);
        const int d3 = *(const int*)(r3 + 16);
        const float al0 = __half2float(*(const __half*)(r0 + (head << 1)));
        const float al1 = __half2float(*(const __half*)(r1 + (head << 1)));
        const float al2 = __half2float(*(const __half*)(r2 + (head << 1)));
        const float al3 = __half2float(*(const __half*)(r3 + (head << 1)));
        const float h0 = __half2float(h16[(size_t)d0 * 64 + lane]);
        const float h1 = __half2float(h16[(size_t)d1 * 64 + lane]);
        const float h2 = __half2float(h16[(size_t)d2 * 64 + lane]);
        const float h3 = __half2float(h16[(size_t)d3 * 64 + lane]);
        acc += al0 * h0 + al1 * h1 + al2 * h2 + al3 * h3;
    }
    for (; e < end; ++e) {
        const char* r = rec + (size_t)e * REC_BYTES;
        acc += __half2float(*(const __half*)(r + (head << 1))) *
               __half2float(h16[(size_t)(*(const int*)(r + 16)) * 64 + lane]);
    }

    // epilogue: residual + LayerNorm + L2 normalize
    float v = acc + xres;
    float s = v;
    #pragma unroll
    for (int off = 1; off < 64; off <<= 1) s += __shfl_xor(s, off);
    const float mu = s * (1.f / 64.f);
    const float d = v - mu;
    float vs = d * d;
    #pragma unroll
    for (int off = 1; off < 64; off <<= 1) vs += __shfl_xor(vs, off);
    const float var = vs * (1.f / 64.f);
    float y = d * rsqrtf(var + LN_EPS) * ln_scale[lane] + ln_bias[lane];
    float ss = y * y;
    #pragma unroll
    for (int off = 1; off < 64; off <<= 1) ss += __shfl_xor(ss, off);
    const float norm = sqrtf(ss);
    out[(size_t)i * 64 + lane] = y / fmaxf(norm, NORM_EPS);
}

// ---------------------------------------------------------------------------
extern "C" void kernel_launch(void* const* d_in, const int* in_sizes, int n_in,
                              void* d_out, int out_size, void* d_ws, size_t ws_size,
                              hipStream_t stream)
{
    const float* x        = (const float*)d_in[0];
    const int*   ei       = (const int*)d_in[1];
    const float* W        = (const float*)d_in[2];
    const float* b        = (const float*)d_in[3];
    const float* a        = (const float*)d_in[4];
    const float* ln_scale = (const float*)d_in[5];
    const float* ln_bias  = (const float*)d_in[6];
    float* out = (float*)d_out;

    char* ws = (char*)d_ws;
    size_t off = 0;
    auto alloc = [&](size_t bytes) {
        void* p = ws + off;
        off = (off + bytes + 255) & ~(size_t)255;
        return p;
    };
    __half* h16       = (__half*)alloc((size_t)N_NODES * 64 * 2);
    float* s_src      = (float*) alloc((size_t)N_NODES * 8 * 4);
    float* s_dst      = (float*) alloc((size_t)N_NODES * 8 * 4);
    int*   counts     = (int*)   alloc((size_t)N_NODES * 4);
    int*   row_ptr    = (int*)   alloc((size_t)(N_NODES + 1) * 4);
    int*   blksum     = (int*)   alloc((size_t)N_TILES * 4);
    int*   gbin       = (int*)   alloc((size_t)NBKT * 4);
    int2*  staged     = (int2*)  alloc((size_t)N_EDGES * 8);
    char*  rec        = (char*)  alloc((size_t)N_EDGES * REC_BYTES);

    hipMemsetAsync(counts, 0, (size_t)N_NODES * 4, stream);

    k_gemm  <<<GEMM_BLOCKS, 256, 0, stream>>>(x, W, b, a, ei, counts,
                                              h16, s_src, s_dst);
    k_scan1 <<<N_TILES, 1024, 0, stream>>>(counts, row_ptr, blksum);
    k_scan23<<<(N_NODES + 255) / 256, 256, 0, stream>>>(row_ptr, blksum, gbin);
    k_bin   <<<BIN_BLOCKS, 1024, 0, stream>>>(ei, gbin, staged);
    k_place <<<NBKT, 1024, 0, stream>>>(row_ptr, staged, s_src, s_dst, rec);
    k_gather<<<(N_NODES + 3) / 4,     256, 0, stream>>>(row_ptr, rec,
                                                        h16, x,
                                                        ln_scale, ln_bias, out);
}

// Round 5
// 254.119 us; speedup vs baseline: 1.6925x; 1.1488x over previous
//
#include <hip/hip_runtime.h>
#include <hip/hip_fp16.h>
#include <math.h>

#define N_NODES 100000
#define N_EDGES 1600000
#define LN_EPS 1e-5f
#define NORM_EPS 1e-12f
#define ROWS_PER_BLOCK 32
#define GEMM_BLOCKS (N_NODES / ROWS_PER_BLOCK)            // 3125, exact
#define WSTRIDE 66   // even (b64-aligned) and 2c+k -> 2-way banks (free)
#define REC_BYTES 32 // final per-edge record {half alpha[8]; int dst; pad}
// R12/R13 ERRATA (measured): scattered partial-line stores pay a full 64B
// fetch+WB PER TOUCH whenever consecutive records of a line are written by
// different workgroups.  Invariant: coalescing happens ONLY when one block
// (one CU/L2) owns all writes to a line.  R14 (WIN, 317->292): bucketed
// counting sort -- k_bin makes block-local runs; k_place owns a 33KB window.
// R15: k_gemm's fused 1.6M random device atomics measured as +49.4MB WRITE
// (= 1.6M x 32B memory-side ops) and ~50us of its 80.6us (VALU 24%, HBM 13%,
// occ 52% -- nothing else saturated).  Node-level counting is redundant
// given buckets: k_hist (LDS-compressed, 294K sequential atomics) + k_bscan
// (1563-scan) replace counts/scan1/scan23; k_place derives per-node row_ptr
// from its own segment.
#define WB 64                                   // nodes per place-bucket
#define NBKT ((N_NODES + WB - 1) / WB)          // 1563
#define BIN_TILE 8192                           // 1024 thr x 8 edges
#define BIN_BLOCKS ((N_EDGES + BIN_TILE - 1) / BIN_TILE)  // 196

// ---------------------------------------------------------------------------
// K1: h = x @ W^T + b (N x 64) -> fp16 (|h|~6 << 65504; 8x less quant error
// than bf16); per-node attn scores fp32.  PURE GEMM now (R15: atomics moved
// out).  K-LOOP DELIBERATELY NOT UNROLLED (#pragma unroll 1): R5/R6 measured
// the unrolled version spilling acc[] at ANY VGPR budget (2.0/0.95 GB scratch
// writes).  No min-waves hint (R5: it's a VGPR cap -> spills).  NO
// nontemporal hints (R9).  NO cooperative launch (R10: grid.sync ~200us).
// ---------------------------------------------------------------------------
__global__ __launch_bounds__(256) void k_gemm(
    const float* __restrict__ x, const float* __restrict__ W,
    const float* __restrict__ b, const float* __restrict__ a,
    __half* __restrict__ h16,
    float* __restrict__ s_src, float* __restrict__ s_dst)
{
    __shared__ float WL[64 * WSTRIDE];            // WL[c*66 + k] = W[c][k]
    __shared__ float xs[ROWS_PER_BLOCK * 64];
    const int tid  = threadIdx.x;
    const int lane = tid & 63;
    const int wv   = tid >> 6;

    for (int idx = tid * 4; idx < 64 * 64; idx += 256 * 4) {
        const float4 w = *(const float4*)(W + idx);
        const int c = idx >> 6, k = idx & 63;
        WL[c * WSTRIDE + k + 0] = w.x;
        WL[c * WSTRIDE + k + 1] = w.y;
        WL[c * WSTRIDE + k + 2] = w.z;
        WL[c * WSTRIDE + k + 3] = w.w;
    }
    const int row0 = blockIdx.x * ROWS_PER_BLOCK;
    for (int idx = tid * 4; idx < ROWS_PER_BLOCK * 64; idx += 256 * 4)
        *(float4*)(xs + idx) = *(const float4*)(x + (size_t)row0 * 64 + idx);
    __syncthreads();

    const float bias = b[lane];
    float acc[8];
    #pragma unroll
    for (int r = 0; r < 8; ++r) acc[r] = bias;

    const int rbase = wv * 8;
    const float* wrow = WL + lane * WSTRIDE;
    const float* xrow = xs + rbase * 64;
    #pragma unroll 1   // DO NOT unroll: keeps live set small (see header)
    for (int kk = 0; kk < 64; kk += 4) {
        const float2 w01 = *(const float2*)(wrow + kk);
        const float2 w23 = *(const float2*)(wrow + kk + 2);
        #pragma unroll
        for (int r = 0; r < 8; ++r) {
            const float4 xq = *(const float4*)(xrow + r * 64 + kk);
            acc[r] += xq.x * w01.x + xq.y * w01.y + xq.z * w23.x + xq.w * w23.y;
        }
    }

    const float asrc = a[(lane >> 3) * 16 + (lane & 7)];
    const float adst = a[(lane >> 3) * 16 + 8 + (lane & 7)];
    #pragma unroll
    for (int r = 0; r < 8; ++r) {
        const int row = row0 + rbase + r;
        const float v = acc[r];
        h16[(size_t)row * 64 + lane] = __float2half_rn(v);
        float p = v * asrc, q = v * adst;
        p += __shfl_xor(p, 1);  q += __shfl_xor(q, 1);
        p += __shfl_xor(p, 2);  q += __shfl_xor(q, 2);
        p += __shfl_xor(p, 4);  q += __shfl_xor(q, 4);
        if ((lane & 7) == 0) {
            s_src[row * 8 + (lane >> 3)] = p;
            s_dst[row * 8 + (lane >> 3)] = q;
        }
    }
}

// ---------------------------------------------------------------------------
// k_hist: bucket-level (src>>6) histogram.  LDS compresses 8192 edges/block
// into <=1563 global atomics with SEQUENTIAL addresses (294K total vs the
// old 1.6M random node atomics).  Reads only the src half of ei (6.4MB).
// ---------------------------------------------------------------------------
__global__ __launch_bounds__(1024) void k_hist(
    const int* __restrict__ ei, int* __restrict__ bhist)
{
    __shared__ int hist[NBKT];
    const int tid = threadIdx.x;
    for (int b = tid; b < NBKT; b += 1024) hist[b] = 0;
    __syncthreads();
    const int e0 = blockIdx.x * BIN_TILE;
    #pragma unroll
    for (int j = 0; j < 8; ++j) {
        const int e = e0 + j * 1024 + tid;
        if (e < N_EDGES) atomicAdd(&hist[ei[e] >> 6], 1);
    }
    __syncthreads();
    for (int b = tid; b < NBKT; b += 1024)
        if (hist[b]) atomicAdd(&bhist[b], hist[b]);
}

// ---------------------------------------------------------------------------
// k_bscan: exclusive scan of the 1563 bucket counts -> bucket_base (segment
// bounds for k_place) + gbin (scatter frontiers for k_bin).  One block,
// two 1024-element wave-scan passes with carry.
// ---------------------------------------------------------------------------
__global__ __launch_bounds__(1024) void k_bscan(
    const int* __restrict__ bhist, int* __restrict__ bucket_base,
    int* __restrict__ gbin)
{
    __shared__ int wsum[16];
    const int tid = threadIdx.x, lane = tid & 63, wv = tid >> 6;

    // chunk 0: elements 0..1023
    int v = (tid < NBKT) ? bhist[tid] : 0;
    int sc = v;
    #pragma unroll
    for (int off = 1; off < 64; off <<= 1) {
        int t = __shfl_up(sc, off);
        if (lane >= off) sc += t;
    }
    if (lane == 63) wsum[wv] = sc;
    __syncthreads();
    if (tid < 16) {
        int ws = wsum[tid];
        #pragma unroll
        for (int off = 1; off < 16; off <<= 1) {
            int t = __shfl_up(ws, off);
            if (tid >= off) ws += t;
        }
        wsum[tid] = ws;
    }
    __syncthreads();
    const int pref0 = wv ? wsum[wv - 1] : 0;
    const int ex0 = pref0 + sc - v;
    if (tid < NBKT) { bucket_base[tid] = ex0; gbin[tid] = ex0; }
    const int T1 = wsum[15];
    __syncthreads();

    // chunk 1: elements 1024..2047
    const int i2 = 1024 + tid;
    int v2 = (i2 < NBKT) ? bhist[i2] : 0;
    int sc2 = v2;
    #pragma unroll
    for (int off = 1; off < 64; off <<= 1) {
        int t = __shfl_up(sc2, off);
        if (lane >= off) sc2 += t;
    }
    if (lane == 63) wsum[wv] = sc2;
    __syncthreads();
    if (tid < 16) {
        int ws = wsum[tid];
        #pragma unroll
        for (int off = 1; off < 16; off <<= 1) {
            int t = __shfl_up(ws, off);
            if (tid >= off) ws += t;
        }
        wsum[tid] = ws;
    }
    __syncthreads();
    const int pref1 = wv ? wsum[wv - 1] : 0;
    const int ex1 = T1 + pref1 + sc2 - v2;
    if (i2 < NBKT) { bucket_base[i2] = ex1; gbin[i2] = ex1; }
    if (tid == 0) bucket_base[NBKT] = N_EDGES;
}

// ---------------------------------------------------------------------------
// k_bin: bucket edges by src>>6.  LDS histogram (atomic return = local
// rank), ONE global atomic per (block,bucket) claims a contiguous run, then
// each thread writes its {src,dst} int2 at base+rank.  Writes within a run
// come from one block -> lines assemble locally (R14-verified).
// ---------------------------------------------------------------------------
__global__ __launch_bounds__(1024) void k_bin(
    const int* __restrict__ ei, int* __restrict__ gbin,
    int2* __restrict__ staged)
{
    __shared__ int hist[NBKT];
    __shared__ int base[NBKT];
    const int tid = threadIdx.x;
    for (int b = tid; b < NBKT; b += 1024) hist[b] = 0;
    __syncthreads();

    int s[8], d[8], r[8];
    const int e0 = blockIdx.x * BIN_TILE;
    #pragma unroll
    for (int j = 0; j < 8; ++j) {
        const int e = e0 + j * 1024 + tid;
        if (e < N_EDGES) {
            s[j] = ei[e];
            d[j] = ei[N_EDGES + e];
            r[j] = atomicAdd(&hist[s[j] >> 6], 1);
        }
    }
    __syncthreads();
    for (int b = tid; b < NBKT; b += 1024)
        if (hist[b]) base[b] = atomicAdd(&gbin[b], hist[b]);
    __syncthreads();
    #pragma unroll
    for (int j = 0; j < 8; ++j) {
        const int e = e0 + j * 1024 + tid;
        if (e < N_EDGES)
            staged[(size_t)base[s[j] >> 6] + r[j]] = make_int2(s[j], d[j]);
    }
}

// ---------------------------------------------------------------------------
// k_place: block g owns nodes [g*64, g*64+64) and segment
// [bucket_base[g], bucket_base[g+1]).  Pass A: LDS histogram of the 64 node
// degrees over the segment + one wave-scan -> writes row_ptr (R15: replaces
// counts/scan1/scan23 entirely).  Pass B (segment re-read, L2-hot 8KB):
// alpha + slot via LDS cursors + record write into the block's EXCLUSIVE
// ~33KB rec window (both records of every 64B line from this block).
// ---------------------------------------------------------------------------
__global__ __launch_bounds__(1024) void k_place(
    const int* __restrict__ bucket_base, const int2* __restrict__ staged,
    const float* __restrict__ s_src, const float* __restrict__ s_dst,
    int* __restrict__ row_ptr, char* __restrict__ rec)
{
    __shared__ int cnt[WB];
    __shared__ int cur[WB];
    const int g   = blockIdx.x;
    const int n0  = g * WB;
    const int tid = threadIdx.x;
    if (tid < WB) cnt[tid] = 0;
    __syncthreads();
    const int beg = bucket_base[g];
    const int end = bucket_base[g + 1];

    for (int j = beg + tid; j < end; j += 1024)
        atomicAdd(&cnt[staged[j].x - n0], 1);
    __syncthreads();
    if (tid < WB) {
        const int c = cnt[tid];
        int sc = c;
        #pragma unroll
        for (int off = 1; off < 64; off <<= 1) {
            int t = __shfl_up(sc, off);
            if (tid >= off) sc += t;
        }
        const int rp = beg + sc - c;     // global exclusive prefix
        cur[tid] = rp;
        if (n0 + tid < N_NODES) row_ptr[n0 + tid] = rp;
    }
    if (g == NBKT - 1 && tid == 0) row_ptr[N_NODES] = N_EDGES;
    __syncthreads();

    for (int j = beg + tid; j < end; j += 1024) {
        const int2 sd = staged[j];
        const int src = sd.x, dst = sd.y;

        const float4 a0 = *(const float4*)(s_src + (size_t)src * 8);
        const float4 a1 = *(const float4*)(s_src + (size_t)src * 8 + 4);
        const float4 b0 = *(const float4*)(s_dst + (size_t)dst * 8);
        const float4 b1 = *(const float4*)(s_dst + (size_t)dst * 8 + 4);
        float sc[8] = {a0.x + b0.x, a0.y + b0.y, a0.z + b0.z, a0.w + b0.w,
                       a1.x + b1.x, a1.y + b1.y, a1.z + b1.z, a1.w + b1.w};
        float m = -1e30f;
        #pragma unroll
        for (int h = 0; h < 8; ++h) {
            sc[h] = (sc[h] >= 0.f) ? sc[h] : 0.2f * sc[h];
            m = fmaxf(m, sc[h]);
        }
        float sum = 0.f;
        #pragma unroll
        for (int h = 0; h < 8; ++h) { sc[h] = __expf(sc[h] - m); sum += sc[h]; }
        const float inv = 1.f / sum;
        unsigned int q[4];
        #pragma unroll
        for (int jj = 0; jj < 4; ++jj) {
            const unsigned short lo = __half_as_ushort(__float2half_rn(sc[2*jj]   * inv));
            const unsigned short hi = __half_as_ushort(__float2half_rn(sc[2*jj+1] * inv));
            q[jj] = (unsigned int)lo | ((unsigned int)hi << 16);
        }

        const int slot = atomicAdd(&cur[src - n0], 1);
        char* rcd = rec + (size_t)slot * REC_BYTES;
        *(uint4*)rcd        = make_uint4(q[0], q[1], q[2], q[3]);
        *(uint4*)(rcd + 16) = make_uint4((unsigned)dst, 0u, 0u, 0u);
    }
}

// ---------------------------------------------------------------------------
// Gather + epilogue: one wave per node; slim loop (~8-10 instrs/edge):
// sequential 32 B record stream (alpha fp16 + dst), random 128 B h16 row
// (L3-resident), FMA.  Identical to R11's verified version.
// ---------------------------------------------------------------------------
__global__ __launch_bounds__(256) void k_gather(
    const int* __restrict__ row_ptr, const char* __restrict__ rec,
    const __half* __restrict__ h16,
    const float* __restrict__ x, const float* __restrict__ ln_scale,
    const float* __restrict__ ln_bias, float* __restrict__ out)
{
    const int i = blockIdx.x * 4 + (threadIdx.x >> 6);
    if (i >= N_NODES) return;
    const int lane = threadIdx.x & 63;
    const int head = lane >> 3;

    const int beg = row_ptr[i];
    const int end = row_ptr[i + 1];
    const float xres = x[(size_t)i * 64 + lane];

    float acc = 0.f;
    int e = beg;
    for (; e + 3 < end; e += 4) {
        const char* r0 = rec + (size_t)(e + 0) * REC_BYTES;
        const char* r1 = rec + (size_t)(e + 1) * REC_BYTES;
        const char* r2 = rec + (size_t)(e + 2) * REC_BYTES;
        const char* r3 = rec + (size_t)(e + 3) * REC_BYTES;
        const int d0 = *(const int*)(r0 + 16);
        const int d1 = *(const int*)(r1 + 16);
        const int d2 = *(const int*)(r2 + 16);
        const int d3 = *(const int*)(r3 + 16);
        const float al0 = __half2float(*(const __half*)(r0 + (head << 1)));
        const float al1 = __half2float(*(const __half*)(r1 + (head << 1)));
        const float al2 = __half2float(*(const __half*)(r2 + (head << 1)));
        const float al3 = __half2float(*(const __half*)(r3 + (head << 1)));
        const float h0 = __half2float(h16[(size_t)d0 * 64 + lane]);
        const float h1 = __half2float(h16[(size_t)d1 * 64 + lane]);
        const float h2 = __half2float(h16[(size_t)d2 * 64 + lane]);
        const float h3 = __half2float(h16[(size_t)d3 * 64 + lane]);
        acc += al0 * h0 + al1 * h1 + al2 * h2 + al3 * h3;
    }
    for (; e < end; ++e) {
        const char* r = rec + (size_t)e * REC_BYTES;
        acc += __half2float(*(const __half*)(r + (head << 1))) *
               __half2float(h16[(size_t)(*(const int*)(r + 16)) * 64 + lane]);
    }

    // epilogue: residual + LayerNorm + L2 normalize
    float v = acc + xres;
    float s = v;
    #pragma unroll
    for (int off = 1; off < 64; off <<= 1) s += __shfl_xor(s, off);
    const float mu = s * (1.f / 64.f);
    const float d = v - mu;
    float vs = d * d;
    #pragma unroll
    for (int off = 1; off < 64; off <<= 1) vs += __shfl_xor(vs, off);
    const float var = vs * (1.f / 64.f);
    float y = d * rsqrtf(var + LN_EPS) * ln_scale[lane] + ln_bias[lane];
    float ss = y * y;
    #pragma unroll
    for (int off = 1; off < 64; off <<= 1) ss += __shfl_xor(ss, off);
    const float norm = sqrtf(ss);
    out[(size_t)i * 64 + lane] = y / fmaxf(norm, NORM_EPS);
}

// ---------------------------------------------------------------------------
extern "C" void kernel_launch(void* const* d_in, const int* in_sizes, int n_in,
                              void* d_out, int out_size, void* d_ws, size_t ws_size,
                              hipStream_t stream)
{
    const float* x        = (const float*)d_in[0];
    const int*   ei       = (const int*)d_in[1];
    const float* W        = (const float*)d_in[2];
    const float* b        = (const float*)d_in[3];
    const float* a        = (const float*)d_in[4];
    const float* ln_scale = (const float*)d_in[5];
    const float* ln_bias  = (const float*)d_in[6];
    float* out = (float*)d_out;

    char* ws = (char*)d_ws;
    size_t off = 0;
    auto alloc = [&](size_t bytes) {
        void* p = ws + off;
        off = (off + bytes + 255) & ~(size_t)255;
        return p;
    };
    __half* h16       = (__half*)alloc((size_t)N_NODES * 64 * 2);
    float* s_src      = (float*) alloc((size_t)N_NODES * 8 * 4);
    float* s_dst      = (float*) alloc((size_t)N_NODES * 8 * 4);
    int*   bhist      = (int*)   alloc((size_t)NBKT * 4);
    int*   bucket_base= (int*)   alloc((size_t)(NBKT + 1) * 4);
    int*   gbin       = (int*)   alloc((size_t)NBKT * 4);
    int*   row_ptr    = (int*)   alloc((size_t)(N_NODES + 1) * 4);
    int2*  staged     = (int2*)  alloc((size_t)N_EDGES * 8);
    char*  rec        = (char*)  alloc((size_t)N_EDGES * REC_BYTES);

    hipMemsetAsync(bhist, 0, (size_t)NBKT * 4, stream);

    k_hist  <<<BIN_BLOCKS, 1024, 0, stream>>>(ei, bhist);
    k_bscan <<<1, 1024, 0, stream>>>(bhist, bucket_base, gbin);
    k_gemm  <<<GEMM_BLOCKS, 256, 0, stream>>>(x, W, b, a, h16, s_src, s_dst);
    k_bin   <<<BIN_BLOCKS, 1024, 0, stream>>>(ei, gbin, staged);
    k_place <<<NBKT, 1024, 0, stream>>>(bucket_base, staged, s_src, s_dst,
                                        row_ptr, rec);
    k_gather<<<(N_NODES + 3) / 4, 256, 0, stream>>>(row_ptr, rec,
                                                    h16, x,
                                                    ln_scale, ln_bias, out);
}